// Round 6
// baseline (249.291 us; speedup 1.0000x reference)
//
#include <hip/hip_runtime.h>
#include <hip/hip_bf16.h>

// ---------------------------------------------------------------------------
// EdgeConvNet — Round 6: persistent waves + 32x32x16 f16 MFMA (4 edges/tile).
//
// Pre-pass: features fp32 -> f16 in d_ws (proven R5: halves gather bytes,
// 6.4 MB table -> high L2 hit).
//
// Main kernel:
//   Persistent: 768 blocks (3/CU), each wave grid-strides over 16-edge
//   groups (4 tiles of 4 edges). Setup (w1 frags, params) paid once per
//   wave (~16 groups). Next group's edge indices preloaded during current
//   group; tile prefetch depth 2 crosses group boundaries (never drains).
//
//   Per tile: C[g][n] = mfma_f32_32x32x16_f16(A=w1 rows 0..15 (16..31 = 0),
//   B=conv), K=64 as 4 chained MFMAs. Both fragments use the SAME
//   (h=lane>>5, elem i)->k map, so any internal k-permutation cancels
//   (validated construction, R3-R5). C/D layout (HW-verified m74/m101):
//   col = lane&31 = n = et*8+ch, row = (reg&3) + 8*(reg>>2) + 4*(lane>>5).
//   -> lane holds 8 of 16 g's in regs 0..7 (rows>=16 are zero, ignored):
//      fc2 = 8 in-lane fma + ONE xor32; fc3 = xor1+xor2+xor4.
// ---------------------------------------------------------------------------

typedef _Float16 f16x8 __attribute__((ext_vector_type(8)));
typedef _Float16 f16x4 __attribute__((ext_vector_type(4)));
typedef _Float16 f16x2 __attribute__((ext_vector_type(2)));
typedef short    bf16x8 __attribute__((ext_vector_type(8)));
typedef float    f32x4  __attribute__((ext_vector_type(4)));
typedef float    f32x2  __attribute__((ext_vector_type(2)));
typedef float    f32x16 __attribute__((ext_vector_type(16)));

union U8 { f16x8 v; f16x2 p[4]; };

static __device__ __forceinline__ short f2bf(float f) {
    union { __hip_bfloat16 h; short s; } u;
    u.h = __float2bfloat16(f);
    return u.s;
}

// ---------------------------- pre-pass ------------------------------------
__global__ __launch_bounds__(256) void feat_to_f16(const float* __restrict__ in,
                                                   _Float16* __restrict__ out,
                                                   int n4) {
    int i = blockIdx.x * blockDim.x + threadIdx.x;
    const int stride = gridDim.x * blockDim.x;
    for (; i < n4; i += stride) {
        const f32x4 v = ((const f32x4*)in)[i];
        ((f16x4*)out)[i] = __builtin_convertvector(v, f16x4);
    }
}

// ---------------------------- main (persistent, 32x32) ---------------------
__global__ __launch_bounds__(256, 3) void edgeconv_f16_p32(
    const _Float16* __restrict__ feat16,     // (50000, 64) f16 (in d_ws)
    const int*      __restrict__ edge_index, // (2, E) int32
    const float* __restrict__ conv_w, const float* __restrict__ conv_b,
    const float* __restrict__ w1,     const float* __restrict__ b1,
    const float* __restrict__ w2,     const float* __restrict__ b2,
    const float* __restrict__ w3,     const float* __restrict__ b3,
    float* __restrict__ out, int nEdges)
{
    const int tid = threadIdx.x;
    const int l   = tid & 63;
    const int wid = tid >> 6;
    const int n   = l & 31;        // B col = A row; n = et*8 + ch
    const int h   = l >> 5;        // k-group (8 elems each)
    const int ch  = n & 7;
    const int et  = n >> 3;        // edge within 4-edge tile

    // --- A fragments: w1[g=n][k], k = j*16 + h*8 + i; rows 16..31 = 0
    f16x8 aw[4];
    #pragma unroll
    for (int j = 0; j < 4; ++j)
        #pragma unroll
        for (int i = 0; i < 8; ++i) aw[j][i] = (_Float16)0.f;
    if (n < 16) {
        const float* w1r = w1 + n * 64 + h * 8;
        #pragma unroll
        for (int j = 0; j < 4; ++j)
            #pragma unroll
            for (int i = 0; i < 8; ++i) aw[j][i] = (_Float16)w1r[j * 16 + i];
    }

    // --- conv params (packed f16 splats)
    const _Float16 cah = (_Float16)conv_w[2 * ch];
    const _Float16 cch = (_Float16)conv_w[2 * ch + 1];
    const _Float16 cbh = (_Float16)conv_b[ch];
    const f16x2 vca = {cah, cah}, vcc = {cch, cch}, vcb = {cbh, cbh};
    const f16x2 vzero = {(_Float16)0.f, (_Float16)0.f};

    // --- epilogue params: regs r=0..7 hold rows g = (r&3) + 4h + 8*(r>>2)
    float b1r[8], w2r[8];
    #pragma unroll
    for (int r = 0; r < 4; ++r) {
        b1r[r]     = b1[4 * h + r];      w2r[r]     = w2[4 * h + r];
        b1r[4 + r] = b1[8 + 4 * h + r];  w2r[4 + r] = w2[8 + 4 * h + r];
    }
    const float w3v = w3[ch];
    const float b2v = b2[0];
    const float b3v = b3[0];

    const int nGroups    = (nEdges + 15) >> 4;
    const int totalWaves = gridDim.x * 4;
    int g = blockIdx.x * 4 + wid;
    if (g >= nGroups) return;

    // per-lane loads for tile T of group with indices (VS,VD):
    // src/dst row chunks j=0..3 at f16 offset j*16 + h*8 (4x 16B each)
#define LOADT(VS, VD, T, BS, BD) do { \
    const int sn_ = __shfl((VS), 4 * (T) + et); \
    const int dn_ = __shfl((VD), 4 * (T) + et); \
    const _Float16* ps_ = feat16 + (size_t)sn_ * 64 + h * 8; \
    const _Float16* pd_ = feat16 + (size_t)dn_ * 64 + h * 8; \
    BS[0] = *(const f16x8*)(ps_);      BS[1] = *(const f16x8*)(ps_ + 16); \
    BS[2] = *(const f16x8*)(ps_ + 32); BS[3] = *(const f16x8*)(ps_ + 48); \
    BD[0] = *(const f16x8*)(pd_);      BD[1] = *(const f16x8*)(pd_ + 16); \
    BD[2] = *(const f16x8*)(pd_ + 32); BD[3] = *(const f16x8*)(pd_ + 48); \
} while (0)

    // prologue: indices for first group, prefetch its tiles 0,1
    int ce = min(g * 16 + (l & 15), nEdges - 1);
    int vs = edge_index[ce];
    int vd = edge_index[nEdges + ce];
    f16x8 bS[2][4], bD[2][4];
    LOADT(vs, vd, 0, bS[0], bD[0]);
    LOADT(vs, vd, 1, bS[1], bD[1]);

    while (true) {
        const int gn = g + totalWaves;
        int vsn = 0, vdn = 0;
        if (gn < nGroups) {                       // preload next group's indices
            const int cen = min(gn * 16 + (l & 15), nEdges - 1);
            vsn = edge_index[cen];
            vdn = edge_index[nEdges + cen];
        }

        #pragma unroll
        for (int t = 0; t < 4; ++t) {
            const int b = t & 1;

            // conv + relu in packed f16 -> B fragments (consume buf b)
            f16x8 bf[4];
            #pragma unroll
            for (int j = 0; j < 4; ++j) {
                U8 s_, d_, o_;
                s_.v = bS[b][j];
                d_.v = bD[b][j];
                #pragma unroll
                for (int p = 0; p < 4; ++p) {
                    f16x2 tt = __builtin_elementwise_fma(vca, s_.p[p],
                                __builtin_elementwise_fma(vcc, d_.p[p], vcb));
                    o_.p[p] = __builtin_elementwise_max(tt, vzero);
                }
                bf[j] = o_.v;
            }

            // prefetch: tiles t+2 of this group, else next group's t-2
            if (t < 2)              LOADT(vs,  vd,  t + 2, bS[b], bD[b]);
            else if (gn < nGroups)  LOADT(vsn, vdn, t - 2, bS[b], bD[b]);

            // fc1: 4 chained MFMAs, fp32 accum
            f32x16 acc = {};
            acc = __builtin_amdgcn_mfma_f32_32x32x16_f16(aw[0], bf[0], acc, 0, 0, 0);
            acc = __builtin_amdgcn_mfma_f32_32x32x16_f16(aw[1], bf[1], acc, 0, 0, 0);
            acc = __builtin_amdgcn_mfma_f32_32x32x16_f16(aw[2], bf[2], acc, 0, 0, 0);
            acc = __builtin_amdgcn_mfma_f32_32x32x16_f16(aw[3], bf[3], acc, 0, 0, 0);

            // fc2: 8 in-lane g-rows + one xor32 to combine halves
            float zp = 0.f;
            #pragma unroll
            for (int r = 0; r < 8; ++r) {
                const float h1 = fmaxf(acc[r] + b1r[r], 0.f);
                zp = fmaf(h1, w2r[r], zp);
            }
            zp += __shfl_xor(zp, 32);

            // fc3: reduce over 8 channels within the octet
            const float h2 = fmaxf(zp + b2v, 0.f);
            float t3 = h2 * w3v;
            t3 += __shfl_xor(t3, 1);
            t3 += __shfl_xor(t3, 2);
            t3 += __shfl_xor(t3, 4);
            const float z  = t3 + b3v;
            const float sg = 1.0f / (1.0f + __expf(-z));

            if (l < 32 && (l & 7) == 0) {         // lanes 0,8,16,24 -> et 0..3
                const int e = g * 16 + 4 * t + et;
                if (e < nEdges) out[e] = sg;
            }
        }

        if (gn >= nGroups) break;
        g = gn; vs = vsn; vd = vdn;
    }
#undef LOADT
}

// ------------------- fallback: round-4 bf16 kernel (proven) ----------------
__global__ __launch_bounds__(256) void edgeconv_mfma2(
    const float* __restrict__ features, const int* __restrict__ edge_index,
    const float* __restrict__ conv_w, const float* __restrict__ conv_b,
    const float* __restrict__ w1, const float* __restrict__ b1,
    const float* __restrict__ w2, const float* __restrict__ b2,
    const float* __restrict__ w3, const float* __restrict__ b3,
    float* __restrict__ out, int nEdges)
{
    const int tid = threadIdx.x;
    const int l   = tid & 63;
    const int wid = tid >> 6;
    const int grp = l >> 4;
    const int n   = l & 15;
    const int ch  = l & 7;
    const int el  = (l >> 3) & 1;

    const float* w1r = w1 + n * 64 + grp * 8;
    bf16x8 aw0, aw1;
    #pragma unroll
    for (int i = 0; i < 8; ++i) {
        aw0[i] = f2bf(w1r[i]);
        aw1[i] = f2bf(w1r[32 + i]);
    }
    const float ca = conv_w[2 * ch];
    const float cc = conv_w[2 * ch + 1];
    const float cb = conv_b[ch];
    float b1r[4], w2r[4];
    #pragma unroll
    for (int r = 0; r < 4; ++r) { b1r[r] = b1[grp * 4 + r]; w2r[r] = w2[grp * 4 + r]; }
    const float w3v = w3[ch];
    const float b2v = b2[0];
    const float b3v = b3[0];

    const int ebase = (blockIdx.x * 4 + wid) * 16;
    const int ce    = min(ebase + n, nEdges - 1);
    const int vs    = edge_index[ce];
    const int vd    = edge_index[nEdges + ce];

#define LOAD_TILE4(T, X1, X2) do { \
    const int sn_ = __shfl(vs, 2 * (T) + el); \
    const int dn_ = __shfl(vd, 2 * (T) + el); \
    const float* p1_ = features + (size_t)sn_ * 64 + grp * 8; \
    const float* p2_ = features + (size_t)dn_ * 64 + grp * 8; \
    X1[0] = *(const f32x4*)(p1_);      X1[1] = *(const f32x4*)(p1_ + 4); \
    X1[2] = *(const f32x4*)(p1_ + 32); X1[3] = *(const f32x4*)(p1_ + 36); \
    X2[0] = *(const f32x4*)(p2_);      X2[1] = *(const f32x4*)(p2_ + 4); \
    X2[2] = *(const f32x4*)(p2_ + 32); X2[3] = *(const f32x4*)(p2_ + 36); \
} while (0)

    f32x4 x1v[4], x2v[4];
    LOAD_TILE4(0, x1v, x2v);
    const f32x2 vca = {ca, ca}, vcc = {cc, cc}, vcb = {cb, cb};
    const f32x2 vz  = {0.f, 0.f};

    #pragma unroll
    for (int t = 0; t < 8; ++t) {
        f32x4 n1v[4], n2v[4];
        if (t < 7) LOAD_TILE4(t + 1, n1v, n2v);
        bf16x8 cf0, cf1;
        #pragma unroll
        for (int p = 0; p < 8; ++p) {
            const int q = p >> 1;
            const int o = (p & 1) * 2;
            f32x2 u = {x1v[q][o], x1v[q][o + 1]};
            f32x2 v = {x2v[q][o], x2v[q][o + 1]};
            f32x2 tt = __builtin_elementwise_fma(vca, u,
                        __builtin_elementwise_fma(vcc, v, vcb));
            tt = __builtin_elementwise_max(tt, vz);
            const short s0 = f2bf(tt[0]), s1 = f2bf(tt[1]);
            if (p < 4) { cf0[2 * (p & 3)] = s0; cf0[2 * (p & 3) + 1] = s1; }
            else       { cf1[2 * (p & 3)] = s0; cf1[2 * (p & 3) + 1] = s1; }
        }
        f32x4 acc = {0.f, 0.f, 0.f, 0.f};
        acc = __builtin_amdgcn_mfma_f32_16x16x32_bf16(aw0, cf0, acc, 0, 0, 0);
        acc = __builtin_amdgcn_mfma_f32_16x16x32_bf16(aw1, cf1, acc, 0, 0, 0);
        float zp = 0.f;
        #pragma unroll
        for (int r = 0; r < 4; ++r) {
            const float h1 = fmaxf(acc[r] + b1r[r], 0.f);
            zp = fmaf(h1, w2r[r], zp);
        }
        zp += __shfl_xor(zp, 16);
        zp += __shfl_xor(zp, 32);
        const float h2 = fmaxf(zp + b2v, 0.f);
        float t3 = h2 * w3v;
        t3 += __shfl_xor(t3, 1);
        t3 += __shfl_xor(t3, 2);
        t3 += __shfl_xor(t3, 4);
        const float z  = t3 + b3v;
        const float sg = 1.0f / (1.0f + __expf(-z));
        if ((l & 55) == 0) {
            const int e = ebase + 2 * t + (l >> 3);
            if (e < nEdges) out[e] = sg;
        }
        if (t < 7) {
            #pragma unroll
            for (int i = 0; i < 4; ++i) { x1v[i] = n1v[i]; x2v[i] = n2v[i]; }
        }
    }
#undef LOAD_TILE4
}

extern "C" void kernel_launch(void* const* d_in, const int* in_sizes, int n_in,
                              void* d_out, int out_size, void* d_ws, size_t ws_size,
                              hipStream_t stream) {
    // 0:x 1:features 2:edge_index 3:conv_w 4:conv_b 5:w1 6:b1 7:w2 8:b2 9:w3 10:b3
    const float* features = (const float*)d_in[1];
    const int*   edge_idx = (const int*)d_in[2];
    const float* conv_w   = (const float*)d_in[3];
    const float* conv_b   = (const float*)d_in[4];
    const float* w1       = (const float*)d_in[5];
    const float* b1       = (const float*)d_in[6];
    const float* w2       = (const float*)d_in[7];
    const float* b2       = (const float*)d_in[8];
    const float* w3       = (const float*)d_in[9];
    const float* b3       = (const float*)d_in[10];
    float*       out      = (float*)d_out;

    const int nEdges = in_sizes[2] / 2;          // (2, E)
    const int nFeat  = in_sizes[1];              // 50000*64

    const size_t need = (size_t)nFeat * sizeof(_Float16);
    if (ws_size >= need) {
        _Float16* feat16 = (_Float16*)d_ws;
        feat_to_f16<<<2048, 256, 0, stream>>>(features, feat16, nFeat / 4);
        // persistent: 3 blocks/CU x 256 CU; each block = 4 waves
        const int nGroups = (nEdges + 15) >> 4;
        const int maxBlocks = 768;
        const int blocks = min(maxBlocks, (nGroups + 3) / 4);
        edgeconv_f16_p32<<<blocks, 256, 0, stream>>>(feat16, edge_idx,
                                                     conv_w, conv_b, w1, b1, w2, b2, w3, b3,
                                                     out, nEdges);
    } else {
        const dim3 grid((nEdges + 63) / 64);
        edgeconv_mfma2<<<grid, 256, 0, stream>>>(features, edge_idx,
                                                 conv_w, conv_b, w1, b1, w2, b2, w3, b3,
                                                 out, nEdges);
    }
}

// Round 7
// 93.092 us; speedup vs baseline: 2.6779x; 2.6779x over previous
//
#include <hip/hip_runtime.h>
#include <hip/hip_bf16.h>

// ---------------------------------------------------------------------------
// EdgeConvNet — Round 7: persistent waves around the PROVEN R5 tile.
//
// R6 lesson (counters): 4-edge/32x32 variant spilled ~170MB to scratch
// (WRITE_SIZE 3->176MB) and launch_bounds(256,3)+768 blocks capped occupancy
// at 33%. R7 keeps R5's 2-edge 16x16x32 f16 tile (52-VGPR state, no spill)
// and adds persistence only:
//   - 2048 blocks (8/CU), 4 waves each; wave grid-strides 16-edge groups.
//   - Setup (w1 frags, conv splats, epilogue params) once per wave.
//   - Next group's indices preloaded at group top; depth-2 tile prefetch
//     crosses the group boundary (t=6,7 load next group's tiles 0,1).
// Pre-pass: features fp32 -> f16 in d_ws (proven: halves gather bytes,
// 6.4 MB table L2/L3-resident).
// ---------------------------------------------------------------------------

typedef _Float16 f16x8 __attribute__((ext_vector_type(8)));
typedef _Float16 f16x4 __attribute__((ext_vector_type(4)));
typedef _Float16 f16x2 __attribute__((ext_vector_type(2)));
typedef short    bf16x8 __attribute__((ext_vector_type(8)));
typedef float    f32x4  __attribute__((ext_vector_type(4)));
typedef float    f32x2  __attribute__((ext_vector_type(2)));

union U8 { f16x8 v; f16x2 p[4]; };

static __device__ __forceinline__ short f2bf(float f) {
    union { __hip_bfloat16 h; short s; } u;
    u.h = __float2bfloat16(f);
    return u.s;
}

// ---------------------------- pre-pass ------------------------------------
__global__ __launch_bounds__(256) void feat_to_f16(const float* __restrict__ in,
                                                   _Float16* __restrict__ out,
                                                   int n4) {
    int i = blockIdx.x * blockDim.x + threadIdx.x;
    const int stride = gridDim.x * blockDim.x;
    for (; i < n4; i += stride) {
        const f32x4 v = ((const f32x4*)in)[i];
        ((f16x4*)out)[i] = __builtin_convertvector(v, f16x4);
    }
}

// ---------------------- main (persistent, R5 tile) -------------------------
__global__ __launch_bounds__(256) void edgeconv_f16_pers(
    const _Float16* __restrict__ feat16,     // (50000, 64) f16 (in d_ws)
    const int*      __restrict__ edge_index, // (2, E) int32
    const float* __restrict__ conv_w, const float* __restrict__ conv_b,
    const float* __restrict__ w1,     const float* __restrict__ b1,
    const float* __restrict__ w2,     const float* __restrict__ b2,
    const float* __restrict__ w3,     const float* __restrict__ b3,
    float* __restrict__ out, int nEdges)
{
    const int tid = threadIdx.x;
    const int l   = tid & 63;
    const int wid = tid >> 6;
    const int grp = l >> 4;        // k-slice group 0..3
    const int n   = l & 15;        // A row = g ; B col = edge·ch
    const int ch  = l & 7;
    const int el  = (l >> 3) & 1;

    // A fragments: w1[g=n][f], f = grp*8+i (+32 for 2nd MFMA), in f16
    const float* w1r = w1 + n * 64 + grp * 8;
    f16x8 aw0, aw1;
    #pragma unroll
    for (int i = 0; i < 8; ++i) {
        aw0[i] = (_Float16)w1r[i];
        aw1[i] = (_Float16)w1r[32 + i];
    }

    // conv params as packed-f16 splats
    const _Float16 cah = (_Float16)conv_w[2 * ch];
    const _Float16 cch = (_Float16)conv_w[2 * ch + 1];
    const _Float16 cbh = (_Float16)conv_b[ch];
    const f16x2 vca = {cah, cah}, vcc = {cch, cch}, vcb = {cbh, cbh};
    const f16x2 vzero = {(_Float16)0.f, (_Float16)0.f};

    float b1r[4], w2r[4];
    #pragma unroll
    for (int r = 0; r < 4; ++r) {
        b1r[r] = b1[grp * 4 + r];
        w2r[r] = w2[grp * 4 + r];
    }
    const float w3v = w3[ch];
    const float b2v = b2[0];
    const float b3v = b3[0];

    const int nGroups    = (nEdges + 15) >> 4;   // 16-edge groups (8 tiles)
    const int totalWaves = gridDim.x * 4;
    int g = blockIdx.x * 4 + wid;
    if (g >= nGroups) return;

    // per tile T of a group with endpoint regs (VS,VD): 4x 16B f16 loads
#define LOADT(VS, VD, T, SLo, SHi, DLo, DHi) do { \
    const int sn_ = __shfl((VS), 2 * (T) + el); \
    const int dn_ = __shfl((VD), 2 * (T) + el); \
    const _Float16* ps_ = feat16 + (size_t)sn_ * 64 + grp * 8; \
    const _Float16* pd_ = feat16 + (size_t)dn_ * 64 + grp * 8; \
    SLo = *(const f16x8*)(ps_);  SHi = *(const f16x8*)(ps_ + 32); \
    DLo = *(const f16x8*)(pd_);  DHi = *(const f16x8*)(pd_ + 32); \
} while (0)

    // prologue: first group's indices; prefetch its tiles 0,1
    {
        const int ce = min(g * 16 + n, nEdges - 1);
        // lanes 0..15 hold the 16 edges; all lanes load (coalesced dup)
    }
    int ce = min(g * 16 + n, nEdges - 1);
    int vs = edge_index[ce];
    int vd = edge_index[nEdges + ce];

    f16x8 sL[2], sH[2], dL[2], dH[2];
    LOADT(vs, vd, 0, sL[0], sH[0], dL[0], dH[0]);
    LOADT(vs, vd, 1, sL[1], sH[1], dL[1], dH[1]);

    while (true) {
        const int gn   = g + totalWaves;
        const bool more = (gn < nGroups);
        int vsn = 0, vdn = 0;
        if (more) {                               // preload next group's indices
            const int cen = min(gn * 16 + n, nEdges - 1);
            vsn = edge_index[cen];
            vdn = edge_index[nEdges + cen];
        }

        #pragma unroll
        for (int t = 0; t < 8; ++t) {
            const int b = t & 1;

            // conv + relu in packed f16 -> B fragments
            U8 s0_, s1_, d0_, d1_, c0, c1;
            s0_.v = sL[b]; s1_.v = sH[b];
            d0_.v = dL[b]; d1_.v = dH[b];
            #pragma unroll
            for (int p = 0; p < 4; ++p) {
                f16x2 tL = __builtin_elementwise_fma(vca, s0_.p[p],
                            __builtin_elementwise_fma(vcc, d0_.p[p], vcb));
                c0.p[p] = __builtin_elementwise_max(tL, vzero);
                f16x2 tH = __builtin_elementwise_fma(vca, s1_.p[p],
                            __builtin_elementwise_fma(vcc, d1_.p[p], vcb));
                c1.p[p] = __builtin_elementwise_max(tH, vzero);
            }

            // prefetch into the buffer just consumed:
            //   t<6: this group's tile t+2 ; t>=6: next group's tile t-6
            if (t < 6)      LOADT(vs,  vd,  t + 2, sL[b], sH[b], dL[b], dH[b]);
            else if (more)  LOADT(vsn, vdn, t - 6, sL[b], sH[b], dL[b], dH[b]);

            // fc1 via MFMA: C[g][n], fp32 accum
            f32x4 acc = {0.f, 0.f, 0.f, 0.f};
            acc = __builtin_amdgcn_mfma_f32_16x16x32_f16(aw0, c0.v, acc, 0, 0, 0);
            acc = __builtin_amdgcn_mfma_f32_16x16x32_f16(aw1, c1.v, acc, 0, 0, 0);

            // fc2: in-lane dot over 4 g-rows, combine the 4 grp groups
            float zp = 0.f;
            #pragma unroll
            for (int r = 0; r < 4; ++r) {
                const float h1 = fmaxf(acc[r] + b1r[r], 0.f);
                zp = fmaf(h1, w2r[r], zp);
            }
            zp += __shfl_xor(zp, 16);
            zp += __shfl_xor(zp, 32);

            // fc3: reduce over 8 channels in the el-octet
            const float h2 = fmaxf(zp + b2v, 0.f);
            float t3 = h2 * w3v;
            t3 += __shfl_xor(t3, 1);
            t3 += __shfl_xor(t3, 2);
            t3 += __shfl_xor(t3, 4);
            const float z  = t3 + b3v;
            const float sg = 1.0f / (1.0f + __expf(-z));

            if ((l & 55) == 0) {                  // lanes 0 (el=0), 8 (el=1)
                const int e = g * 16 + 2 * t + (l >> 3);
                if (e < nEdges) out[e] = sg;
            }
        }

        if (!more) break;
        g = gn; vs = vsn; vd = vdn;
    }
#undef LOADT
}

// ------------------- fallback: round-4 bf16 kernel (proven) ----------------
__global__ __launch_bounds__(256) void edgeconv_mfma2(
    const float* __restrict__ features, const int* __restrict__ edge_index,
    const float* __restrict__ conv_w, const float* __restrict__ conv_b,
    const float* __restrict__ w1, const float* __restrict__ b1,
    const float* __restrict__ w2, const float* __restrict__ b2,
    const float* __restrict__ w3, const float* __restrict__ b3,
    float* __restrict__ out, int nEdges)
{
    const int tid = threadIdx.x;
    const int l   = tid & 63;
    const int wid = tid >> 6;
    const int grp = l >> 4;
    const int n   = l & 15;
    const int ch  = l & 7;
    const int el  = (l >> 3) & 1;

    const float* w1r = w1 + n * 64 + grp * 8;
    bf16x8 aw0, aw1;
    #pragma unroll
    for (int i = 0; i < 8; ++i) {
        aw0[i] = f2bf(w1r[i]);
        aw1[i] = f2bf(w1r[32 + i]);
    }
    const float ca = conv_w[2 * ch];
    const float cc = conv_w[2 * ch + 1];
    const float cb = conv_b[ch];
    float b1r[4], w2r[4];
    #pragma unroll
    for (int r = 0; r < 4; ++r) { b1r[r] = b1[grp * 4 + r]; w2r[r] = w2[grp * 4 + r]; }
    const float w3v = w3[ch];
    const float b2v = b2[0];
    const float b3v = b3[0];

    const int ebase = (blockIdx.x * 4 + wid) * 16;
    const int ce    = min(ebase + n, nEdges - 1);
    const int vs    = edge_index[ce];
    const int vd    = edge_index[nEdges + ce];

#define LOAD_TILE4(T, X1, X2) do { \
    const int sn_ = __shfl(vs, 2 * (T) + el); \
    const int dn_ = __shfl(vd, 2 * (T) + el); \
    const float* p1_ = features + (size_t)sn_ * 64 + grp * 8; \
    const float* p2_ = features + (size_t)dn_ * 64 + grp * 8; \
    X1[0] = *(const f32x4*)(p1_);      X1[1] = *(const f32x4*)(p1_ + 4); \
    X1[2] = *(const f32x4*)(p1_ + 32); X1[3] = *(const f32x4*)(p1_ + 36); \
    X2[0] = *(const f32x4*)(p2_);      X2[1] = *(const f32x4*)(p2_ + 4); \
    X2[2] = *(const f32x4*)(p2_ + 32); X2[3] = *(const f32x4*)(p2_ + 36); \
} while (0)

    f32x4 x1v[4], x2v[4];
    LOAD_TILE4(0, x1v, x2v);
    const f32x2 vca = {ca, ca}, vcc = {cc, cc}, vcb = {cb, cb};
    const f32x2 vz  = {0.f, 0.f};

    #pragma unroll
    for (int t = 0; t < 8; ++t) {
        f32x4 n1v[4], n2v[4];
        if (t < 7) LOAD_TILE4(t + 1, n1v, n2v);
        bf16x8 cf0, cf1;
        #pragma unroll
        for (int p = 0; p < 8; ++p) {
            const int q = p >> 1;
            const int o = (p & 1) * 2;
            f32x2 u = {x1v[q][o], x1v[q][o + 1]};
            f32x2 v = {x2v[q][o], x2v[q][o + 1]};
            f32x2 tt = __builtin_elementwise_fma(vca, u,
                        __builtin_elementwise_fma(vcc, v, vcb));
            tt = __builtin_elementwise_max(tt, vz);
            const short s0 = f2bf(tt[0]), s1 = f2bf(tt[1]);
            if (p < 4) { cf0[2 * (p & 3)] = s0; cf0[2 * (p & 3) + 1] = s1; }
            else       { cf1[2 * (p & 3)] = s0; cf1[2 * (p & 3) + 1] = s1; }
        }
        f32x4 acc = {0.f, 0.f, 0.f, 0.f};
        acc = __builtin_amdgcn_mfma_f32_16x16x32_bf16(aw0, cf0, acc, 0, 0, 0);
        acc = __builtin_amdgcn_mfma_f32_16x16x32_bf16(aw1, cf1, acc, 0, 0, 0);
        float zp = 0.f;
        #pragma unroll
        for (int r = 0; r < 4; ++r) {
            const float h1 = fmaxf(acc[r] + b1r[r], 0.f);
            zp = fmaf(h1, w2r[r], zp);
        }
        zp += __shfl_xor(zp, 16);
        zp += __shfl_xor(zp, 32);
        const float h2 = fmaxf(zp + b2v, 0.f);
        float t3 = h2 * w3v;
        t3 += __shfl_xor(t3, 1);
        t3 += __shfl_xor(t3, 2);
        t3 += __shfl_xor(t3, 4);
        const float z  = t3 + b3v;
        const float sg = 1.0f / (1.0f + __expf(-z));
        if ((l & 55) == 0) {
            const int e = ebase + 2 * t + (l >> 3);
            if (e < nEdges) out[e] = sg;
        }
        if (t < 7) {
            #pragma unroll
            for (int i = 0; i < 4; ++i) { x1v[i] = n1v[i]; x2v[i] = n2v[i]; }
        }
    }
#undef LOAD_TILE4
}

extern "C" void kernel_launch(void* const* d_in, const int* in_sizes, int n_in,
                              void* d_out, int out_size, void* d_ws, size_t ws_size,
                              hipStream_t stream) {
    // 0:x 1:features 2:edge_index 3:conv_w 4:conv_b 5:w1 6:b1 7:w2 8:b2 9:w3 10:b3
    const float* features = (const float*)d_in[1];
    const int*   edge_idx = (const int*)d_in[2];
    const float* conv_w   = (const float*)d_in[3];
    const float* conv_b   = (const float*)d_in[4];
    const float* w1       = (const float*)d_in[5];
    const float* b1       = (const float*)d_in[6];
    const float* w2       = (const float*)d_in[7];
    const float* b2       = (const float*)d_in[8];
    const float* w3       = (const float*)d_in[9];
    const float* b3       = (const float*)d_in[10];
    float*       out      = (float*)d_out;

    const int nEdges = in_sizes[2] / 2;          // (2, E)
    const int nFeat  = in_sizes[1];              // 50000*64

    const size_t need = (size_t)nFeat * sizeof(_Float16);
    if (ws_size >= need) {
        _Float16* feat16 = (_Float16*)d_ws;
        feat_to_f16<<<2048, 256, 0, stream>>>(features, feat16, nFeat / 4);
        // persistent: 2048 blocks (8/CU target), 4 waves each, grid-stride
        const int nGroups = (nEdges + 15) >> 4;
        const int blocks  = min(2048, (nGroups + 3) / 4);
        edgeconv_f16_pers<<<blocks, 256, 0, stream>>>(feat16, edge_idx,
                                                      conv_w, conv_b, w1, b1, w2, b2, w3, b3,
                                                      out, nEdges);
    } else {
        const dim3 grid((nEdges + 63) / 64);
        edgeconv_mfma2<<<grid, 256, 0, stream>>>(features, edge_idx,
                                                 conv_w, conv_b, w1, b1, w2, b2, w3, b3,
                                                 out, nEdges);
    }
}

// Round 8
// 86.379 us; speedup vs baseline: 2.8860x; 1.0777x over previous
//
#include <hip/hip_runtime.h>
#include <hip/hip_bf16.h>

// ---------------------------------------------------------------------------
// EdgeConvNet — Round 8: batched epilogue (8 independent shuffle chains).
//
// R7 analysis: per-tile serial chain of 5 dependent shuffles (~150cy dead
// per tile) with ~2.3 waves/SIMD overlap -> 60% VALUBusy, 570cy/tile.
// R8 splits each 8-tile group into:
//   phase 1 (per tile): conv (v_pk_fma_f16) -> MFMA -> in-lane fc2 partial
//            zp[t]; depth-2 prefetch as before. No cross-lane ops.
//   phase 2 (all 8 tiles, pass-wise): xor16 x8, xor32 x8, relu*w3 x8,
//            xor1 x8, xor2 x8, xor4 x8, sigmoid x8, store x8.
//   Each pass = 8 independent shuffles -> latency mutually hidden.
// Everything else identical to R7 (persistent waves, f16 pre-pass, proven
// 16x16x32 f16 MFMA tile with swapped operands).
// ---------------------------------------------------------------------------

typedef _Float16 f16x8 __attribute__((ext_vector_type(8)));
typedef _Float16 f16x4 __attribute__((ext_vector_type(4)));
typedef _Float16 f16x2 __attribute__((ext_vector_type(2)));
typedef short    bf16x8 __attribute__((ext_vector_type(8)));
typedef float    f32x4  __attribute__((ext_vector_type(4)));
typedef float    f32x2  __attribute__((ext_vector_type(2)));

union U8 { f16x8 v; f16x2 p[4]; };

static __device__ __forceinline__ short f2bf(float f) {
    union { __hip_bfloat16 h; short s; } u;
    u.h = __float2bfloat16(f);
    return u.s;
}

// ---------------------------- pre-pass ------------------------------------
__global__ __launch_bounds__(256) void feat_to_f16(const float* __restrict__ in,
                                                   _Float16* __restrict__ out,
                                                   int n4) {
    int i = blockIdx.x * blockDim.x + threadIdx.x;
    const int stride = gridDim.x * blockDim.x;
    for (; i < n4; i += stride) {
        const f32x4 v = ((const f32x4*)in)[i];
        ((f16x4*)out)[i] = __builtin_convertvector(v, f16x4);
    }
}

// ---------------- main (persistent, batched epilogue) ----------------------
__global__ __launch_bounds__(256) void edgeconv_f16_be(
    const _Float16* __restrict__ feat16,     // (50000, 64) f16 (in d_ws)
    const int*      __restrict__ edge_index, // (2, E) int32
    const float* __restrict__ conv_w, const float* __restrict__ conv_b,
    const float* __restrict__ w1,     const float* __restrict__ b1,
    const float* __restrict__ w2,     const float* __restrict__ b2,
    const float* __restrict__ w3,     const float* __restrict__ b3,
    float* __restrict__ out, int nEdges)
{
    const int tid = threadIdx.x;
    const int l   = tid & 63;
    const int wid = tid >> 6;
    const int grp = l >> 4;        // k-slice group 0..3
    const int n   = l & 15;        // A row = g ; B col = edge·ch
    const int ch  = l & 7;
    const int el  = (l >> 3) & 1;

    // A fragments: w1[g=n][f], f = grp*8+i (+32 for 2nd MFMA), in f16
    const float* w1r = w1 + n * 64 + grp * 8;
    f16x8 aw0, aw1;
    #pragma unroll
    for (int i = 0; i < 8; ++i) {
        aw0[i] = (_Float16)w1r[i];
        aw1[i] = (_Float16)w1r[32 + i];
    }

    // conv params as packed-f16 splats
    const _Float16 cah = (_Float16)conv_w[2 * ch];
    const _Float16 cch = (_Float16)conv_w[2 * ch + 1];
    const _Float16 cbh = (_Float16)conv_b[ch];
    const f16x2 vca = {cah, cah}, vcc = {cch, cch}, vcb = {cbh, cbh};
    const f16x2 vzero = {(_Float16)0.f, (_Float16)0.f};

    float b1r[4], w2r[4];
    #pragma unroll
    for (int r = 0; r < 4; ++r) {
        b1r[r] = b1[grp * 4 + r];
        w2r[r] = w2[grp * 4 + r];
    }
    const float w3v = w3[ch];
    const float b2v = b2[0];
    const float b3v = b3[0];

    const int nGroups    = (nEdges + 15) >> 4;   // 16-edge groups (8 tiles)
    const int totalWaves = gridDim.x * 4;
    int g = blockIdx.x * 4 + wid;
    if (g >= nGroups) return;

#define LOADT(VS, VD, T, SLo, SHi, DLo, DHi) do { \
    const int sn_ = __shfl((VS), 2 * (T) + el); \
    const int dn_ = __shfl((VD), 2 * (T) + el); \
    const _Float16* ps_ = feat16 + (size_t)sn_ * 64 + grp * 8; \
    const _Float16* pd_ = feat16 + (size_t)dn_ * 64 + grp * 8; \
    SLo = *(const f16x8*)(ps_);  SHi = *(const f16x8*)(ps_ + 32); \
    DLo = *(const f16x8*)(pd_);  DHi = *(const f16x8*)(pd_ + 32); \
} while (0)

    // prologue: first group's indices; prefetch its tiles 0,1
    int ce = min(g * 16 + n, nEdges - 1);
    int vs = edge_index[ce];
    int vd = edge_index[nEdges + ce];

    f16x8 sL[2], sH[2], dL[2], dH[2];
    LOADT(vs, vd, 0, sL[0], sH[0], dL[0], dH[0]);
    LOADT(vs, vd, 1, sL[1], sH[1], dL[1], dH[1]);

    while (true) {
        const int gn    = g + totalWaves;
        const bool more = (gn < nGroups);
        int vsn = 0, vdn = 0;
        if (more) {                               // preload next group's indices
            const int cen = min(gn * 16 + n, nEdges - 1);
            vsn = edge_index[cen];
            vdn = edge_index[nEdges + cen];
        }

        // ---------------- phase 1: conv + MFMA + in-lane fc2 ----------------
        float zp[8];
        #pragma unroll
        for (int t = 0; t < 8; ++t) {
            const int b = t & 1;

            U8 s0_, s1_, d0_, d1_, c0, c1;
            s0_.v = sL[b]; s1_.v = sH[b];
            d0_.v = dL[b]; d1_.v = dH[b];
            #pragma unroll
            for (int p = 0; p < 4; ++p) {
                f16x2 tL = __builtin_elementwise_fma(vca, s0_.p[p],
                            __builtin_elementwise_fma(vcc, d0_.p[p], vcb));
                c0.p[p] = __builtin_elementwise_max(tL, vzero);
                f16x2 tH = __builtin_elementwise_fma(vca, s1_.p[p],
                            __builtin_elementwise_fma(vcc, d1_.p[p], vcb));
                c1.p[p] = __builtin_elementwise_max(tH, vzero);
            }

            // prefetch into buffer just consumed (crosses group boundary)
            if (t < 6)      LOADT(vs,  vd,  t + 2, sL[b], sH[b], dL[b], dH[b]);
            else if (more)  LOADT(vsn, vdn, t - 6, sL[b], sH[b], dL[b], dH[b]);

            f32x4 acc = {0.f, 0.f, 0.f, 0.f};
            acc = __builtin_amdgcn_mfma_f32_16x16x32_f16(aw0, c0.v, acc, 0, 0, 0);
            acc = __builtin_amdgcn_mfma_f32_16x16x32_f16(aw1, c1.v, acc, 0, 0, 0);

            float z_ = 0.f;
            #pragma unroll
            for (int r = 0; r < 4; ++r) {
                const float h1 = fmaxf(acc[r] + b1r[r], 0.f);
                z_ = fmaf(h1, w2r[r], z_);
            }
            zp[t] = z_;
        }

        // ---------------- phase 2: batched shuffle reduces ------------------
        #pragma unroll
        for (int t = 0; t < 8; ++t) zp[t] += __shfl_xor(zp[t], 16);
        #pragma unroll
        for (int t = 0; t < 8; ++t) zp[t] += __shfl_xor(zp[t], 32);
        #pragma unroll
        for (int t = 0; t < 8; ++t) {
            const float h2 = fmaxf(zp[t] + b2v, 0.f);
            zp[t] = h2 * w3v;
        }
        #pragma unroll
        for (int t = 0; t < 8; ++t) zp[t] += __shfl_xor(zp[t], 1);
        #pragma unroll
        for (int t = 0; t < 8; ++t) zp[t] += __shfl_xor(zp[t], 2);
        #pragma unroll
        for (int t = 0; t < 8; ++t) zp[t] += __shfl_xor(zp[t], 4);
        #pragma unroll
        for (int t = 0; t < 8; ++t) {
            const float z  = zp[t] + b3v;
            const float sg = 1.0f / (1.0f + __expf(-z));
            if ((l & 55) == 0) {                  // lanes 0 (el=0), 8 (el=1)
                const int e = g * 16 + 2 * t + (l >> 3);
                if (e < nEdges) out[e] = sg;
            }
        }

        if (!more) break;
        g = gn; vs = vsn; vd = vdn;
    }
#undef LOADT
}

// ------------------- fallback: round-4 bf16 kernel (proven) ----------------
__global__ __launch_bounds__(256) void edgeconv_mfma2(
    const float* __restrict__ features, const int* __restrict__ edge_index,
    const float* __restrict__ conv_w, const float* __restrict__ conv_b,
    const float* __restrict__ w1, const float* __restrict__ b1,
    const float* __restrict__ w2, const float* __restrict__ b2,
    const float* __restrict__ w3, const float* __restrict__ b3,
    float* __restrict__ out, int nEdges)
{
    const int tid = threadIdx.x;
    const int l   = tid & 63;
    const int wid = tid >> 6;
    const int grp = l >> 4;
    const int n   = l & 15;
    const int ch  = l & 7;
    const int el  = (l >> 3) & 1;

    const float* w1r = w1 + n * 64 + grp * 8;
    bf16x8 aw0, aw1;
    #pragma unroll
    for (int i = 0; i < 8; ++i) {
        aw0[i] = f2bf(w1r[i]);
        aw1[i] = f2bf(w1r[32 + i]);
    }
    const float ca = conv_w[2 * ch];
    const float cc = conv_w[2 * ch + 1];
    const float cb = conv_b[ch];
    float b1r[4], w2r[4];
    #pragma unroll
    for (int r = 0; r < 4; ++r) { b1r[r] = b1[grp * 4 + r]; w2r[r] = w2[grp * 4 + r]; }
    const float w3v = w3[ch];
    const float b2v = b2[0];
    const float b3v = b3[0];

    const int ebase = (blockIdx.x * 4 + wid) * 16;
    const int ce    = min(ebase + n, nEdges - 1);
    const int vs    = edge_index[ce];
    const int vd    = edge_index[nEdges + ce];

#define LOAD_TILE4(T, X1, X2) do { \
    const int sn_ = __shfl(vs, 2 * (T) + el); \
    const int dn_ = __shfl(vd, 2 * (T) + el); \
    const float* p1_ = features + (size_t)sn_ * 64 + grp * 8; \
    const float* p2_ = features + (size_t)dn_ * 64 + grp * 8; \
    X1[0] = *(const f32x4*)(p1_);      X1[1] = *(const f32x4*)(p1_ + 4); \
    X1[2] = *(const f32x4*)(p1_ + 32); X1[3] = *(const f32x4*)(p1_ + 36); \
    X2[0] = *(const f32x4*)(p2_);      X2[1] = *(const f32x4*)(p2_ + 4); \
    X2[2] = *(const f32x4*)(p2_ + 32); X2[3] = *(const f32x4*)(p2_ + 36); \
} while (0)

    f32x4 x1v[4], x2v[4];
    LOAD_TILE4(0, x1v, x2v);
    const f32x2 vca = {ca, ca}, vcc = {cc, cc}, vcb = {cb, cb};
    const f32x2 vz  = {0.f, 0.f};

    #pragma unroll
    for (int t = 0; t < 8; ++t) {
        f32x4 n1v[4], n2v[4];
        if (t < 7) LOAD_TILE4(t + 1, n1v, n2v);
        bf16x8 cf0, cf1;
        #pragma unroll
        for (int p = 0; p < 8; ++p) {
            const int q = p >> 1;
            const int o = (p & 1) * 2;
            f32x2 u = {x1v[q][o], x1v[q][o + 1]};
            f32x2 v = {x2v[q][o], x2v[q][o + 1]};
            f32x2 tt = __builtin_elementwise_fma(vca, u,
                        __builtin_elementwise_fma(vcc, v, vcb));
            tt = __builtin_elementwise_max(tt, vz);
            const short s0 = f2bf(tt[0]), s1 = f2bf(tt[1]);
            if (p < 4) { cf0[2 * (p & 3)] = s0; cf0[2 * (p & 3) + 1] = s1; }
            else       { cf1[2 * (p & 3)] = s0; cf1[2 * (p & 3) + 1] = s1; }
        }
        f32x4 acc = {0.f, 0.f, 0.f, 0.f};
        acc = __builtin_amdgcn_mfma_f32_16x16x32_bf16(aw0, cf0, acc, 0, 0, 0);
        acc = __builtin_amdgcn_mfma_f32_16x16x32_bf16(aw1, cf1, acc, 0, 0, 0);
        float zp = 0.f;
        #pragma unroll
        for (int r = 0; r < 4; ++r) {
            const float h1 = fmaxf(acc[r] + b1r[r], 0.f);
            zp = fmaf(h1, w2r[r], zp);
        }
        zp += __shfl_xor(zp, 16);
        zp += __shfl_xor(zp, 32);
        const float h2 = fmaxf(zp + b2v, 0.f);
        float t3 = h2 * w3v;
        t3 += __shfl_xor(t3, 1);
        t3 += __shfl_xor(t3, 2);
        t3 += __shfl_xor(t3, 4);
        const float z  = t3 + b3v;
        const float sg = 1.0f / (1.0f + __expf(-z));
        if ((l & 55) == 0) {
            const int e = ebase + 2 * t + (l >> 3);
            if (e < nEdges) out[e] = sg;
        }
        if (t < 7) {
            #pragma unroll
            for (int i = 0; i < 4; ++i) { x1v[i] = n1v[i]; x2v[i] = n2v[i]; }
        }
    }
#undef LOAD_TILE4
}

extern "C" void kernel_launch(void* const* d_in, const int* in_sizes, int n_in,
                              void* d_out, int out_size, void* d_ws, size_t ws_size,
                              hipStream_t stream) {
    // 0:x 1:features 2:edge_index 3:conv_w 4:conv_b 5:w1 6:b1 7:w2 8:b2 9:w3 10:b3
    const float* features = (const float*)d_in[1];
    const int*   edge_idx = (const int*)d_in[2];
    const float* conv_w   = (const float*)d_in[3];
    const float* conv_b   = (const float*)d_in[4];
    const float* w1       = (const float*)d_in[5];
    const float* b1       = (const float*)d_in[6];
    const float* w2       = (const float*)d_in[7];
    const float* b2       = (const float*)d_in[8];
    const float* w3       = (const float*)d_in[9];
    const float* b3       = (const float*)d_in[10];
    float*       out      = (float*)d_out;

    const int nEdges = in_sizes[2] / 2;          // (2, E)
    const int nFeat  = in_sizes[1];              // 50000*64

    const size_t need = (size_t)nFeat * sizeof(_Float16);
    if (ws_size >= need) {
        _Float16* feat16 = (_Float16*)d_ws;
        feat_to_f16<<<2048, 256, 0, stream>>>(features, feat16, nFeat / 4);
        const int nGroups = (nEdges + 15) >> 4;
        const int blocks  = min(2048, (nGroups + 3) / 4);
        edgeconv_f16_be<<<blocks, 256, 0, stream>>>(feat16, edge_idx,
                                                    conv_w, conv_b, w1, b1, w2, b2, w3, b3,
                                                    out, nEdges);
    } else {
        const dim3 grid((nEdges + 63) / 64);
        edgeconv_mfma2<<<grid, 256, 0, stream>>>(features, edge_idx,
                                                 conv_w, conv_b, w1, b1, w2, b2, w3, b3,
                                                 out, nEdges);
    }
}